// Round 1
// 79.281 us; speedup vs baseline: 1.0022x; 1.0022x over previous
//
#include <hip/hip_runtime.h>

// S4D kernel generation: K[h,l] = 2*Re( sum_n Ceff[h,n] * exp(dtA[h,n]*l) )
//   dtA = A*dt, A = -exp(log_A_real) + i*A_imag, dt = exp(log_dt)
//   Ceff = C * (exp(dtA)-1)/A
//
// R3 structure: TWO blocks per h (grid=2048, block=256). Block jb in {0,1}
// owns the 8 coalesced outputs l = tid + 2048*jb + 256*j, j in [0,8).
//   * z = exp(dtA*t'), t' = tid + 2048*jb; ratio w = exp(256*dtA) between j's.
//   * u_j = 2Re(Ceff z w^j) obeys u_j = 2Re(w) u_{j-1} - |w|^2 u_{j-2}.
//   * u_1 via rotation of (u_0, v_0=2Im(Ceff z)): 4 pk ops, no full z*w.
//   * Phase reduction is PURE f32: rb split into rh (multiple of 2^-8, so
//     rh*t' is EXACT in f32 for t' < 4096) + rl (|rl| <= 2^-9). Phase in
//     revolutions feeds native v_fract/v_sin/v_cos — no fp64, no 1/2pi muls.
//   * NJ=8 halves acc registers & the serial chain vs R2; __launch_bounds__
//     (256,8) targets <=64 VGPR -> 8 waves/SIMD (2x occupancy of R2).
//   * #pragma unroll 1 on the np loop keeps the live set (8 v2 consts +
//     acc[8] + temps) within the 64-VGPR budget.

#define HD   1024
#define NS   32
#define LL   4096
#define BLK  256
#define JBLK 2                    // blocks per h
#define NJ   (LL / (BLK * JBLK))  // 8
#define GRID (HD * JBLK)

typedef float v2 __attribute__((ext_vector_type(2)));

__global__ __launch_bounds__(BLK, 8) void s4d_kernel(
    const float* __restrict__ log_dt,
    const float* __restrict__ C_ri,
    const float* __restrict__ log_A_real,
    const float* __restrict__ A_imag,
    float* __restrict__ K)
{
    const int bid = blockIdx.x;
    const int h   = bid >> 1;
    const int jb  = bid & 1;
    const int tid = threadIdx.x;

    // Pair layout: slot (n&15)*2 + (n>>4) so pair np holds n=np (x), n=np+16 (y).
    __shared__ v2 s_wr[NS / 2], s_wi[NS / 2];     // w = exp(256*dtA)
    __shared__ v2 s_q[NS / 2];                    // |w|^2
    __shared__ v2 s_c2r[NS / 2], s_c2i[NS / 2];   // 2*Ceff (re, im)
    __shared__ v2 s_al2[NS / 2];                  // Re(dtA)*log2(e)
    __shared__ v2 s_rh[NS / 2], s_rl[NS / 2];     // Im(dtA)/2pi split hi/lo

    const double TWO_PI     = 6.283185307179586;
    const double INV_TWO_PI = 0.15915494309189535;

    if (tid < NS) {
        const int   n   = tid;
        const int   sl  = ((n & 15) << 1) | (n >> 4);
        const float dt  = expf(log_dt[h]);
        const float ar  = -expf(log_A_real[h * NS + n]);   // Re(A)
        const float ai  = A_imag[h * NS + n];              // Im(A)
        const float a   = ar * dt;                         // Re(dtA)
        const double bd = (double)ai * (double)dt;         // Im(dtA)
        const float b   = (float)bd;

        // exp(dtA) - 1
        const float e = expf(a);
        float sb, cb;
        sincosf(b, &sb, &cb);
        const float er = fmaf(e, cb, -1.0f);
        const float ei = e * sb;

        // (er + i*ei) / (ar + i*ai)
        const float den = fmaf(ar, ar, ai * ai);
        const float inv = 1.0f / den;
        const float fr  = fmaf(er, ar,  ei * ai) * inv;
        const float fi  = fmaf(ei, ar, -er * ai) * inv;

        const float Cr = C_ri[(h * NS + n) * 2 + 0];
        const float Ci = C_ri[(h * NS + n) * 2 + 1];
        ((float*)s_c2r)[sl] = 2.0f * fmaf(Cr, fr, -Ci * fi);
        ((float*)s_c2i)[sl] = 2.0f * fmaf(Cr, fi,  Ci * fr);

        // w = exp(256*dtA), phase reduced mod 2pi in fp64 (prologue only)
        double ph = bd * 256.0;
        ph -= floor(ph * INV_TWO_PI) * TWO_PI;
        float sw, cw;
        sincosf((float)ph, &sw, &cw);
        const float e256 = expf(a * 256.0f);
        ((float*)s_wr)[sl]  = e256 * cw;
        ((float*)s_wi)[sl]  = e256 * sw;
        ((float*)s_q)[sl]   = e256 * e256;
        ((float*)s_al2)[sl] = a * 1.4426950408889634f;

        // revolutions-per-l split: rh multiple of 2^-8 (exact f32 products
        // for t' < 4096), rl = residual, |rl| <= 2^-9.
        const double rbd = bd * INV_TWO_PI;
        const double rhd = rint(rbd * 256.0) * 0.00390625;  // /256
        ((float*)s_rh)[sl] = (float)rhd;
        ((float*)s_rl)[sl] = (float)(rbd - rhd);
    }
    __syncthreads();

    v2 acc[NJ];
#pragma unroll
    for (int j = 0; j < NJ; ++j) acc[j] = (v2)(0.0f);

    const float t = (float)(tid + (jb << 11));   // t' = tid + 2048*jb

#pragma unroll 1
    for (int np = 0; np < NS / 2; ++np) {
        const v2 al2 = s_al2[np];
        const v2 wr  = s_wr[np];
        const v2 wi  = s_wi[np];
        const v2 q   = s_q[np];
        const v2 c2r = s_c2r[np];
        const v2 c2i = s_c2i[np];
        const v2 rh  = s_rh[np];
        const v2 rl  = s_rl[np];

        // |z| via hw exp2; phase (revolutions) via exact hi/lo reduction
        v2 mag, ph;
        mag.x = __builtin_amdgcn_exp2f(al2.x * t);
        mag.y = __builtin_amdgcn_exp2f(al2.y * t);
        ph.x  = __builtin_amdgcn_fractf(fmaf(rl.x, t, __builtin_amdgcn_fractf(rh.x * t)));
        ph.y  = __builtin_amdgcn_fractf(fmaf(rl.y, t, __builtin_amdgcn_fractf(rh.y * t)));

        v2 zr, zi;
        zr.x = mag.x * __builtin_amdgcn_cosf(ph.x);
        zr.y = mag.y * __builtin_amdgcn_cosf(ph.y);
        zi.x = mag.x * __builtin_amdgcn_sinf(ph.x);
        zi.y = mag.y * __builtin_amdgcn_sinf(ph.y);

        // u0 = 2Re(Cz), v0 = 2Im(Cz), u1 = wr*u0 - wi*v0 = 2Re(Czw)
        v2 u0 = c2r * zr - c2i * zi;
        v2 vv = c2r * zi + c2i * zr;
        v2 u1 = wr * u0 - wi * vv;
        const v2 p = wr + wr;   // 2*Re(w)

        acc[0] += u0;
        acc[1] += u1;
#pragma unroll
        for (int j = 2; j < NJ; ++j) {
            const v2 u = p * u1 - q * u0;
            acc[j] += u;
            u0 = u1;
            u1 = u;
        }
    }

    float* out = K + h * LL + (jb << 11) + tid;
#pragma unroll
    for (int j = 0; j < NJ; ++j) out[j * BLK] = acc[j].x + acc[j].y;
}

extern "C" void kernel_launch(void* const* d_in, const int* in_sizes, int n_in,
                              void* d_out, int out_size, void* d_ws, size_t ws_size,
                              hipStream_t stream) {
    // d_in[0] = L (int scalar, == 4096, hard-coded)
    const float* log_dt     = (const float*)d_in[1];
    const float* C_ri       = (const float*)d_in[2];
    const float* log_A_real = (const float*)d_in[3];
    const float* A_imag     = (const float*)d_in[4];
    float* K = (float*)d_out;

    s4d_kernel<<<dim3(GRID), dim3(BLK), 0, stream>>>(log_dt, C_ri, log_A_real, A_imag, K);
}